// Round 5
// baseline (373.693 us; speedup 1.0000x reference)
//
#include <hip/hip_runtime.h>

typedef __attribute__((ext_vector_type(8))) short bf16x8;
typedef __attribute__((ext_vector_type(4))) float f32x4;
typedef unsigned int u32;
typedef unsigned short u16;

__device__ __forceinline__ u16 f2bf(float f) {
  u32 u = __float_as_uint(f);
  u += 0x7fffu + ((u >> 16) & 1u);   // RNE
  return (u16)(u >> 16);
}
__device__ __forceinline__ u32 pack2(float a, float b) {
  return (u32)f2bf(a) | ((u32)f2bf(b) << 16);
}
__device__ __forceinline__ void gload_lds16(const void* g, void* l) {
  __builtin_amdgcn_global_load_lds(
      (const __attribute__((address_space(1))) u32*)g,
      (__attribute__((address_space(3))) u32*)l, 16, 0, 0);
}

// ---------------- pre-pass: f32 -> bf16 (K, W) ----------------
__global__ void cvt_bf16_kernel(const float* __restrict__ in, u16* __restrict__ out,
                                long long n8) {
  long long i = (long long)blockIdx.x * blockDim.x + threadIdx.x;
  if (i >= n8) return;
  const float4* p = (const float4*)in + i * 2;
  float4 a = p[0], b = p[1];
  uint4 o;
  o.x = pack2(a.x, a.y); o.y = pack2(a.z, a.w);
  o.z = pack2(b.x, b.y); o.w = pack2(b.z, b.w);
  ((uint4*)out)[i] = o;
}

// ---------------- pre-pass: V[b][n][d] -> Vt[b][d][n] (bf16) ----------------
__global__ __launch_bounds__(256)
void transpose_v_kernel(const float* __restrict__ V, u16* __restrict__ Vt) {
  __shared__ float tile[64][65];
  const int n0 = blockIdx.x * 64, d0 = blockIdx.y * 64, bat = blockIdx.z;
  const int t = threadIdx.x;
  const int rr = t >> 4, cc = (t & 15) * 4;
#pragma unroll
  for (int i = 0; i < 4; ++i) {
    int r = i * 16 + rr;
    float4 v = *(const float4*)(V + ((size_t)(bat * 2048 + n0 + r)) * 512 + d0 + cc);
    tile[r][cc + 0] = v.x; tile[r][cc + 1] = v.y;
    tile[r][cc + 2] = v.z; tile[r][cc + 3] = v.w;
  }
  __syncthreads();
#pragma unroll
  for (int i = 0; i < 4; ++i) {
    int dr = i * 16 + rr;
    uint2 o;
    o.x = pack2(tile[cc + 0][dr], tile[cc + 1][dr]);
    o.y = pack2(tile[cc + 2][dr], tile[cc + 3][dr]);
    *(uint2*)(Vt + ((size_t)(bat * 512 + d0 + dr)) * 2048 + n0 + cc) = o;
  }
}

// ------- fused flash attention + projection:
//   R = relu(softmax(QK^T*s) @ V);  Out = a*R + b*relu((V-R) @ W^T)
// Round-0 structure; QK^T retiled to 32q x 16kv per wave so ONE K B-read
// feeds TWO MFMAs (B-stream halved: 256 -> 128 ds_read_b128 per CU-iter).
// qf[32] = 128 VGPRs; launch_bounds(512) [no min-occ] -> 256-reg cap
// (2048 regs / 8 waves); occupancy stays LDS-capped at 8 waves/CU.
// LDS layout (bytes):
//  Ks0 [64][512] bf16 XOR-swz  @0       (65536)   (Q scratch in prologue; T=V-R in epilogue)
//  Ks1 [64][512] bf16 XOR-swz  @65536   (65536)
//  Ss  [64][68]  f32           @131072  (17408)
//  Ps  [64][..144B] bf16       @148480  (9216)
//  mrow/lrow/resc f32[64]      @158720/158976/159232
//  flags u32[8]                @159488
#define ATT_LDS 159552

__global__ __launch_bounds__(512)
void attn_kernel(const float* __restrict__ Qf, const u16* __restrict__ Kb,
                 const u16* __restrict__ Vtg, const float* __restrict__ Vg,
                 const u16* __restrict__ Wb, const float* __restrict__ sp,
                 const float* __restrict__ ap, const float* __restrict__ bp,
                 float* __restrict__ Out) {
  extern __shared__ char smem[];
  u16* Ks0 = (u16*)smem;
  u16* Ks1 = (u16*)(smem + 65536);
  float* Ss = (float*)(smem + 131072);
  u16* Ps = (u16*)(smem + 148480);
  float* mrow = (float*)(smem + 158720);
  float* lrow = (float*)(smem + 158976);
  float* resc = (float*)(smem + 159232);
  u32* flg = (u32*)(smem + 159488);

  const int tid = threadIdx.x, lane = tid & 63, wid = tid >> 6;
  const int bat = blockIdx.x, q0 = blockIdx.y * 64;  // flat%8 == bat -> per-XCD batch locality
  const float scale = sp[0] * 0.04419417382415922f;  // 1/sqrt(512)
  const int l15 = lane & 15, l4 = lane >> 4;
  const int srow = tid >> 3, sseg = tid & 7;
  const int qg = wid >> 2, kg = wid & 3;  // QK^T wave tile: 32 q-rows x 16 kv-cols

  // ---- prologue: stage Q (pre-scaled) f32 -> bf16 swizzled into Ks0 scratch ----
  {
    const float* qsrc = Qf + ((size_t)(bat * 2048 + q0 + srow)) * 512;
    char* qdst = (char*)Ks0 + srow * 1024;
    const int sw = (srow & 7) << 4;
#pragma unroll
    for (int j = 0; j < 8; ++j) {
      int sc = sseg * 8 + j;
      float4 x0 = *(const float4*)(qsrc + sc * 8);
      float4 x1 = *(const float4*)(qsrc + sc * 8 + 4);
      uint4 w;
      w.x = pack2(x0.x * scale, x0.y * scale); w.y = pack2(x0.z * scale, x0.w * scale);
      w.z = pack2(x1.x * scale, x1.y * scale); w.w = pack2(x1.z * scale, x1.w * scale);
      *(uint4*)(qdst + ((sc * 16) ^ sw)) = w;
    }
  }
  __syncthreads();

  // ---- load persistent Q A-fragments (32 q-rows per wave -> qf = 128 VGPRs) ----
  // qf[ks]   : rows qg*32 +  0..15, k-slice ks
  // qf[16+ks]: rows qg*32 + 16..31, k-slice ks
  bf16x8 qf[32];
  {
    const char* qb0 = (const char*)Ks0 + (qg * 32 + l15) * 1024;
    const char* qb1 = qb0 + 16 * 1024;
    const int swA = (l15 & 7) << 4;
#pragma unroll
    for (int ks = 0; ks < 16; ++ks) {
      const int off = (ks * 64 + l4 * 16) ^ swA;
      qf[ks] = *(const bf16x8*)(qb0 + off);
      qf[16 + ks] = *(const bf16x8*)(qb1 + off);
    }
  }
  __syncthreads();  // frag reads done before K(0) overwrites Ks0 scratch

  // ---- stage K(0) via global_load_lds (source pre-swizzled per lane) ----
#pragma unroll
  for (int j = 0; j < 8; ++j) {
    int row = wid * 8 + j;
    gload_lds16(Kb + ((size_t)(bat * 2048 + row)) * 512 + ((lane ^ (row & 7)) * 8),
                (char*)Ks0 + row * 1024);
  }
  if (tid < 64) { mrow[tid] = -1e30f; lrow[tid] = 0.f; }

  f32x4 o[4][4];
#pragma unroll
  for (int a = 0; a < 4; ++a)
#pragma unroll
    for (int b = 0; b < 4; ++b) o[a][b] = (f32x4){0.f, 0.f, 0.f, 0.f};

  __syncthreads();  // K(0) resident + visible

  const int swB = (l15 & 7) << 4;

  for (int it = 0; it < 32; ++it) {
    const u16* Kcur = (it & 1) ? Ks1 : Ks0;
    u16* Knxt = (it & 1) ? Ks0 : Ks1;

    // ---- [top] V(it) -> vregs (oldest in vmem queue; cover = QK^T) ----
    uint4 vreg[8];
#pragma unroll
    for (int cf = 0; cf < 4; ++cf)
#pragma unroll
      for (int s = 0; s < 2; ++s)
        vreg[cf * 2 + s] = *(const uint4*)(Vtg +
            ((size_t)(bat * 512 + wid * 64 + cf * 16 + l15)) * 2048 +
            it * 64 + s * 32 + l4 * 8);

    // ---- [top] K(it+1) -> Ks[nxt] via gload_lds (cover = QK^T; drains at bar1) ----
    if (it < 31) {
      const int kv1 = (it + 1) * 64;
#pragma unroll
      for (int j = 0; j < 8; ++j) {
        int row = wid * 8 + j;
        gload_lds16(Kb + ((size_t)(bat * 2048 + kv1 + row)) * 512 + ((lane ^ (row & 7)) * 8),
                    (char*)Knxt + row * 1024);
      }
    }
    __builtin_amdgcn_sched_barrier(0);  // pin all load issues above QK^T

    // ---- QK^T: wave = 32 q-rows x 16 kv-cols, K=512, A from registers ----
    // one K B-fragment read feeds TWO MFMAs (q-rows 0..15 and 16..31)
    {
      f32x4 s0 = (f32x4){0.f, 0.f, 0.f, 0.f};
      f32x4 s1 = (f32x4){0.f, 0.f, 0.f, 0.f};
      const char* kb = (const char*)Kcur + (kg * 16 + l15) * 1024;
#pragma unroll
      for (int ks = 0; ks < 16; ++ks) {
        const int off = (ks * 64 + l4 * 16) ^ swB;
        bf16x8 b = *(const bf16x8*)(kb + off);
        s0 = __builtin_amdgcn_mfma_f32_16x16x32_bf16(qf[ks], b, s0, 0, 0, 0);
        s1 = __builtin_amdgcn_mfma_f32_16x16x32_bf16(qf[16 + ks], b, s1, 0, 0, 0);
      }
      const int r0 = qg * 32 + l4 * 4;
      const int c0 = kg * 16 + l15;
#pragma unroll
      for (int j = 0; j < 4; ++j) {
        Ss[(r0 + j) * 68 + c0] = s0[j];
        Ss[(r0 + 16 + j) * 68 + c0] = s1[j];
      }
    }
    __syncthreads();  // bar1: Ss visible; K(it+1)/V(it) drained (full QK^T cover)

    // ---- online softmax with defer-max (THR=8): 8 threads/row, 16 cols each ----
    {
      const int row = srow, g = sseg;
      float4 sv0 = *(const float4*)(Ss + row * 68 + g * 8);
      float4 sv1 = *(const float4*)(Ss + row * 68 + g * 8 + 4);
      float mt = fmaxf(fmaxf(fmaxf(sv0.x, sv0.y), fmaxf(sv0.z, sv0.w)),
                       fmaxf(fmaxf(sv1.x, sv1.y), fmaxf(sv1.z, sv1.w)));
#pragma unroll
      for (int off = 1; off < 8; off <<= 1) mt = fmaxf(mt, __shfl_xor(mt, off));
      const float mold = mrow[row];
      const bool exceed = (mt > mold + 8.0f);
      const float mnew = exceed ? mt : mold;  // deferred max; P bounded by e^8
      float p0 = __expf(sv0.x - mnew), p1 = __expf(sv0.y - mnew);
      float p2 = __expf(sv0.z - mnew), p3 = __expf(sv0.w - mnew);
      float p4 = __expf(sv1.x - mnew), p5 = __expf(sv1.y - mnew);
      float p6 = __expf(sv1.z - mnew), p7 = __expf(sv1.w - mnew);
      float ps = ((p0 + p1) + (p2 + p3)) + ((p4 + p5) + (p6 + p7));
#pragma unroll
      for (int off = 1; off < 8; off <<= 1) ps += __shfl_xor(ps, off);
      if (g == 0) {
        float rs = exceed ? __expf(mold - mnew) : 1.0f;
        resc[row] = rs;
        lrow[row] = lrow[row] * rs + ps;
        mrow[row] = mnew;
      }
      int ex = __any(g == 0 && exceed);  // wave-uniform
      if (lane == 0) flg[wid] = ex ? 1u : 0u;
      uint4 pw;
      pw.x = pack2(p0, p1); pw.y = pack2(p2, p3);
      pw.z = pack2(p4, p5); pw.w = pack2(p6, p7);
      *(uint4*)((char*)Ps + row * 144 + g * 16) = pw;
    }
    __syncthreads();  // bar2: Ps + flags visible

    // ---- PV: conditional rescale, then wave = 64 q-rows x 64 d-cols, k=64 ----
    {
      const uint4* fp = (const uint4*)flg;
      uint4 fa = fp[0], fb = fp[1];
      u32 anyr = fa.x | fa.y | fa.z | fa.w | fb.x | fb.y | fb.z | fb.w;
      if (anyr) {
#pragma unroll
        for (int fr = 0; fr < 4; ++fr) {
          f32x4 rf = *(const f32x4*)(resc + fr * 16 + l4 * 4);
#pragma unroll
          for (int cf = 0; cf < 4; ++cf)
#pragma unroll
            for (int j = 0; j < 4; ++j) o[fr][cf][j] *= rf[j];
        }
      }
#pragma unroll
      for (int s = 0; s < 2; ++s) {
        bf16x8 pa[4];
#pragma unroll
        for (int fr = 0; fr < 4; ++fr)
          pa[fr] = *(const bf16x8*)((const char*)Ps + (fr * 16 + l15) * 144 + s * 64 + l4 * 16);
#pragma unroll
        for (int fr = 0; fr < 4; ++fr)
#pragma unroll
          for (int cf = 0; cf < 4; ++cf)
            o[fr][cf] = __builtin_amdgcn_mfma_f32_16x16x32_bf16(
                pa[fr], *(const bf16x8*)&vreg[cf * 2 + s], o[fr][cf], 0, 0, 0);
      }
    }
    // no trailing barrier (hazards ordered by bar1/bar2 of adjacent iterations)
  }

  // ======== fused epilogue ========
  // R = relu(O/l) in regs; T = V-R -> Ts (bf16, swizzled, reuse Ks0);
  // C = T @ W^T; Out = a*R + b*relu(C)
  const float av = ap[0], bv = bp[0];
#pragma unroll
  for (int fr = 0; fr < 4; ++fr) {
    f32x4 lv = *(const f32x4*)(lrow + fr * 16 + l4 * 4);
    f32x4 inv;
#pragma unroll
    for (int j = 0; j < 4; ++j) inv[j] = 1.f / lv[j];
#pragma unroll
    for (int cf = 0; cf < 4; ++cf)
#pragma unroll
      for (int j = 0; j < 4; ++j)
        o[fr][cf][j] = fmaxf(o[fr][cf][j] * inv[j], 0.f);  // o now holds R
  }
  // write T = V - R into Ts (swizzled bf16). Last Ks0 read was QK^T(30): safe.
  {
    u16* Ts = Ks0;
#pragma unroll
    for (int fr = 0; fr < 4; ++fr)
#pragma unroll
      for (int cf = 0; cf < 4; ++cf) {
        const int col = wid * 64 + cf * 16 + l15;
#pragma unroll
        for (int j = 0; j < 4; ++j) {
          const int row = fr * 16 + l4 * 4 + j;
          float v = Vg[((size_t)(bat * 2048 + q0 + row)) * 512 + col];
          u16 t = f2bf(v - o[fr][cf][j]);
          *(u16*)((char*)Ts + row * 1024 + ((col * 2) ^ ((row & 7) << 4))) = t;
        }
      }
  }
  __syncthreads();  // T tile complete

  // projection GEMM: wave owns 64q x 64o (o-cols wid*64..+64), k=512
  f32x4 c2[4][4];
#pragma unroll
  for (int a = 0; a < 4; ++a)
#pragma unroll
    for (int b = 0; b < 4; ++b) c2[a][b] = (f32x4){0.f, 0.f, 0.f, 0.f};
  {
    const u16* Ts = Ks0;
#pragma unroll
    for (int ks = 0; ks < 16; ++ks) {
      bf16x8 aT[4];
#pragma unroll
      for (int fr = 0; fr < 4; ++fr) {
        const int row = fr * 16 + l15;
        aT[fr] = *(const bf16x8*)((const char*)Ts + row * 1024 +
                                  ((ks * 64 + l4 * 16) ^ ((row & 7) << 4)));
      }
#pragma unroll
      for (int cf = 0; cf < 4; ++cf) {
        const int orow = wid * 64 + cf * 16 + l15;
        bf16x8 bw = *(const bf16x8*)(Wb + (size_t)orow * 512 + ks * 32 + l4 * 8);
#pragma unroll
        for (int fr = 0; fr < 4; ++fr)
          c2[fr][cf] = __builtin_amdgcn_mfma_f32_16x16x32_bf16(aT[fr], bw, c2[fr][cf], 0, 0, 0);
      }
    }
  }
  // combine + store
#pragma unroll
  for (int fr = 0; fr < 4; ++fr)
#pragma unroll
    for (int cf = 0; cf < 4; ++cf) {
      const int col = wid * 64 + cf * 16 + l15;
#pragma unroll
      for (int j = 0; j < 4; ++j) {
        const int row = fr * 16 + l4 * 4 + j;
        float c = fmaxf(c2[fr][cf][j], 0.f);
        Out[((size_t)(bat * 2048 + q0 + row)) * 512 + col] = av * o[fr][cf][j] + bv * c;
      }
    }
}

extern "C" void kernel_launch(void* const* d_in, const int* in_sizes, int n_in,
                              void* d_out, int out_size, void* d_ws, size_t ws_size,
                              hipStream_t stream) {
  const float* Q = (const float*)d_in[0];
  const float* K = (const float*)d_in[1];
  const float* V = (const float*)d_in[2];
  const float* W = (const float*)d_in[3];
  const float* sp = (const float*)d_in[4];
  const float* ap = (const float*)d_in[5];
  const float* bp = (const float*)d_in[6];
  float* out = (float*)d_out;

  const long long tEl = 8LL * 2048 * 512;  // 8388608 elems per tensor
  u16* Kb = (u16*)d_ws;
  u16* Vt = Kb + tEl;
  u16* Wb = Vt + tEl;

  cvt_bf16_kernel<<<4096, 256, 0, stream>>>(K, Kb, tEl / 8);
  cvt_bf16_kernel<<<128, 256, 0, stream>>>(W, Wb, (512LL * 512) / 8);
  transpose_v_kernel<<<dim3(32, 8, 8), 256, 0, stream>>>(V, Vt);

  hipFuncSetAttribute(reinterpret_cast<const void*>(attn_kernel),
                      hipFuncAttributeMaxDynamicSharedMemorySize, ATT_LDS);
  attn_kernel<<<dim3(8, 32), 512, ATT_LDS, stream>>>(Q, Kb, Vt, V, Wb, sp, ap, bp, out);
}

// Round 6
// 183.005 us; speedup vs baseline: 2.0420x; 2.0420x over previous
//
#include <hip/hip_runtime.h>

typedef __attribute__((ext_vector_type(8))) short bf16x8;
typedef __attribute__((ext_vector_type(4))) float f32x4;
typedef unsigned int u32;
typedef unsigned short u16;

__device__ __forceinline__ u16 f2bf(float f) {
  u32 u = __float_as_uint(f);
  u += 0x7fffu + ((u >> 16) & 1u);   // RNE
  return (u16)(u >> 16);
}
__device__ __forceinline__ u32 pack2(float a, float b) {
  return (u32)f2bf(a) | ((u32)f2bf(b) << 16);
}
__device__ __forceinline__ void gload_lds16(const void* g, void* l) {
  __builtin_amdgcn_global_load_lds(
      (const __attribute__((address_space(1))) u32*)g,
      (__attribute__((address_space(3))) u32*)l, 16, 0, 0);
}

// ---------------- pre-pass: f32 -> bf16 (K, W) ----------------
__global__ void cvt_bf16_kernel(const float* __restrict__ in, u16* __restrict__ out,
                                long long n8) {
  long long i = (long long)blockIdx.x * blockDim.x + threadIdx.x;
  if (i >= n8) return;
  const float4* p = (const float4*)in + i * 2;
  float4 a = p[0], b = p[1];
  uint4 o;
  o.x = pack2(a.x, a.y); o.y = pack2(a.z, a.w);
  o.z = pack2(b.x, b.y); o.w = pack2(b.z, b.w);
  ((uint4*)out)[i] = o;
}

// ---------------- pre-pass: V[b][n][d] -> Vt[b][d][n] (bf16) ----------------
__global__ __launch_bounds__(256)
void transpose_v_kernel(const float* __restrict__ V, u16* __restrict__ Vt) {
  __shared__ float tile[64][65];
  const int n0 = blockIdx.x * 64, d0 = blockIdx.y * 64, bat = blockIdx.z;
  const int t = threadIdx.x;
  const int rr = t >> 4, cc = (t & 15) * 4;
#pragma unroll
  for (int i = 0; i < 4; ++i) {
    int r = i * 16 + rr;
    float4 v = *(const float4*)(V + ((size_t)(bat * 2048 + n0 + r)) * 512 + d0 + cc);
    tile[r][cc + 0] = v.x; tile[r][cc + 1] = v.y;
    tile[r][cc + 2] = v.z; tile[r][cc + 3] = v.w;
  }
  __syncthreads();
#pragma unroll
  for (int i = 0; i < 4; ++i) {
    int dr = i * 16 + rr;
    uint2 o;
    o.x = pack2(tile[cc + 0][dr], tile[cc + 1][dr]);
    o.y = pack2(tile[cc + 2][dr], tile[cc + 3][dr]);
    *(uint2*)(Vt + ((size_t)(bat * 512 + d0 + dr)) * 2048 + n0 + cc) = o;
  }
}

// ------- fused flash attention + projection (16 waves/CU variant):
//   R = relu(softmax(QK^T*s) @ V);  Out = a*R + b*relu((V-R) @ W^T)
// r0 structure, KVBLK cut 64->32 so LDS fits TWO 512-thread blocks per CU
// (16 waves/CU, 4/SIMD, 2 independent barrier domains -> latency overlap).
// QK^T even/odd split accumulators keep 2 MFMA chains despite 16kv tiles.
// LDS layout (bytes), total 80672 (<= 81920 = 160K/2):
//  Ks0 [32][1024B] bf16 XOR-swz @0      (32768)  (Ks0..Ks1 64KB span holds
//  Ks1 [32][1024B] bf16 XOR-swz @32768  (32768)   Q scratch / T=V-R tile)
//  Ss  [64][36] f32             @65536  (9216)
//  Ps  [64][80B] bf16           @74752  (5120)
//  mrow/lrow/resc f32[64]       @79872/80128/80384
//  flags u32[8]                 @80640
#define ATT_LDS 80672

__global__ __launch_bounds__(512, 2)
void attn_kernel(const float* __restrict__ Qf, const u16* __restrict__ Kb,
                 const u16* __restrict__ Vtg, const float* __restrict__ Vg,
                 const u16* __restrict__ Wb, const float* __restrict__ sp,
                 const float* __restrict__ ap, const float* __restrict__ bp,
                 float* __restrict__ Out) {
  extern __shared__ char smem[];
  u16* Ks0 = (u16*)smem;
  u16* Ks1 = (u16*)(smem + 32768);
  float* Ss = (float*)(smem + 65536);
  u16* Ps = (u16*)(smem + 74752);
  float* mrow = (float*)(smem + 79872);
  float* lrow = (float*)(smem + 80128);
  float* resc = (float*)(smem + 80384);
  u32* flg = (u32*)(smem + 80640);

  const int tid = threadIdx.x, lane = tid & 63, wid = tid >> 6;
  const int bat = blockIdx.x, q0 = blockIdx.y * 64;  // per-XCD batch locality
  const float scale = sp[0] * 0.04419417382415922f;  // 1/sqrt(512)
  const int l15 = lane & 15, l4 = lane >> 4;
  const int srow = tid >> 3, sseg = tid & 7;
  const int rwD = wid >> 1, cwD = wid & 1;  // QK^T wave tile: 16 q-rows x 16 kv-cols

  // ---- prologue: stage Q (pre-scaled) f32 -> bf16 swizzled into Ks0..Ks1 span ----
  {
    const float* qsrc = Qf + ((size_t)(bat * 2048 + q0 + srow)) * 512;
    char* qdst = smem + srow * 1024;  // 64 rows x 1KB = full 64KB span
    const int sw = (srow & 7) << 4;
#pragma unroll
    for (int j = 0; j < 8; ++j) {
      int sc = sseg * 8 + j;
      float4 x0 = *(const float4*)(qsrc + sc * 8);
      float4 x1 = *(const float4*)(qsrc + sc * 8 + 4);
      uint4 w;
      w.x = pack2(x0.x * scale, x0.y * scale); w.y = pack2(x0.z * scale, x0.w * scale);
      w.z = pack2(x1.x * scale, x1.y * scale); w.w = pack2(x1.z * scale, x1.w * scale);
      *(uint4*)(qdst + ((sc * 16) ^ sw)) = w;
    }
  }
  __syncthreads();

  // ---- load persistent Q A-fragments (16 q-rows per wave -> qf = 64 VGPRs) ----
  bf16x8 qf[16];
  {
    const char* qb = smem + (rwD * 16 + l15) * 1024;
    const int swA = (l15 & 7) << 4;
#pragma unroll
    for (int ks = 0; ks < 16; ++ks)
      qf[ks] = *(const bf16x8*)(qb + ((ks * 64 + l4 * 16) ^ swA));
  }
  __syncthreads();  // frag reads done before K(0) overwrites the scratch

  // ---- stage K(0) (32 rows) via global_load_lds (source pre-swizzled per lane) ----
#pragma unroll
  for (int j = 0; j < 4; ++j) {
    int row = wid * 4 + j;
    gload_lds16(Kb + ((size_t)(bat * 2048 + row)) * 512 + ((lane ^ (row & 7)) * 8),
                (char*)Ks0 + row * 1024);
  }
  if (tid < 64) { mrow[tid] = -1e30f; lrow[tid] = 0.f; }

  f32x4 o[4][4];
#pragma unroll
  for (int a = 0; a < 4; ++a)
#pragma unroll
    for (int b = 0; b < 4; ++b) o[a][b] = (f32x4){0.f, 0.f, 0.f, 0.f};

  __syncthreads();  // K(0) resident + visible

  const int swB = (l15 & 7) << 4;

  for (int it = 0; it < 64; ++it) {
    const u16* Kcur = (it & 1) ? Ks1 : Ks0;
    u16* Knxt = (it & 1) ? Ks0 : Ks1;

    // ---- [top] V(it) -> vregs (cover = QK^T); wave owns d-cols wid*64..+64 ----
    uint4 vreg[4];
#pragma unroll
    for (int cf = 0; cf < 4; ++cf)
      vreg[cf] = *(const uint4*)(Vtg +
          ((size_t)(bat * 512 + wid * 64 + cf * 16 + l15)) * 2048 +
          it * 32 + l4 * 8);

    // ---- [top] K(it+1) -> Ks[nxt] via gload_lds (drains at bar1) ----
    if (it < 63) {
      const int kv1 = (it + 1) * 32;
#pragma unroll
      for (int j = 0; j < 4; ++j) {
        int row = wid * 4 + j;
        gload_lds16(Kb + ((size_t)(bat * 2048 + kv1 + row)) * 512 + ((lane ^ (row & 7)) * 8),
                    (char*)Knxt + row * 1024);
      }
    }
    __builtin_amdgcn_sched_barrier(0);  // pin all load issues above QK^T

    // ---- QK^T: wave = 16 q-rows x 16 kv-cols, K=512, even/odd acc chains ----
    {
      f32x4 se = (f32x4){0.f, 0.f, 0.f, 0.f};
      f32x4 so = (f32x4){0.f, 0.f, 0.f, 0.f};
      const char* kb = (const char*)Kcur + (cwD * 16 + l15) * 1024;
      __builtin_amdgcn_s_setprio(1);
#pragma unroll
      for (int ks = 0; ks < 16; ks += 2) {
        const int offe = (ks * 64 + l4 * 16) ^ swB;
        const int offo = ((ks + 1) * 64 + l4 * 16) ^ swB;
        bf16x8 be = *(const bf16x8*)(kb + offe);
        bf16x8 bo = *(const bf16x8*)(kb + offo);
        se = __builtin_amdgcn_mfma_f32_16x16x32_bf16(qf[ks], be, se, 0, 0, 0);
        so = __builtin_amdgcn_mfma_f32_16x16x32_bf16(qf[ks + 1], bo, so, 0, 0, 0);
      }
      __builtin_amdgcn_s_setprio(0);
      f32x4 s = se + so;
      const int r0 = rwD * 16 + l4 * 4;
      const int c0 = cwD * 16 + l15;
#pragma unroll
      for (int j = 0; j < 4; ++j) Ss[(r0 + j) * 36 + c0] = s[j];
    }
    __syncthreads();  // bar1: Ss visible; K(it+1)/V(it) drained

    // ---- online softmax with defer-max (THR=8): 8 threads/row, 4 cols each ----
    {
      const int row = srow, g = sseg;
      float4 sv = *(const float4*)(Ss + row * 36 + g * 4);
      float mt = fmaxf(fmaxf(sv.x, sv.y), fmaxf(sv.z, sv.w));
#pragma unroll
      for (int off = 1; off < 8; off <<= 1) mt = fmaxf(mt, __shfl_xor(mt, off));
      const float mold = mrow[row];
      const bool exceed = (mt > mold + 8.0f);
      const float mnew = exceed ? mt : mold;  // deferred max; P bounded by e^8
      float p0 = __expf(sv.x - mnew), p1 = __expf(sv.y - mnew);
      float p2 = __expf(sv.z - mnew), p3 = __expf(sv.w - mnew);
      float ps = (p0 + p1) + (p2 + p3);
#pragma unroll
      for (int off = 1; off < 8; off <<= 1) ps += __shfl_xor(ps, off);
      if (g == 0) {
        float rs = exceed ? __expf(mold - mnew) : 1.0f;
        resc[row] = rs;
        lrow[row] = lrow[row] * rs + ps;
        mrow[row] = mnew;
      }
      int ex = __any(g == 0 && exceed);  // wave-uniform
      if (lane == 0) flg[wid] = ex ? 1u : 0u;
      uint2 pw;
      pw.x = pack2(p0, p1); pw.y = pack2(p2, p3);
      *(uint2*)((char*)Ps + row * 80 + g * 8) = pw;
    }
    __syncthreads();  // bar2: Ps + flags visible

    // ---- PV: conditional rescale, then wave = 64 q-rows x 64 d-cols, k=32 ----
    {
      const uint4* fp = (const uint4*)flg;
      uint4 fa = fp[0], fb = fp[1];
      u32 anyr = fa.x | fa.y | fa.z | fa.w | fb.x | fb.y | fb.z | fb.w;
      if (anyr) {
#pragma unroll
        for (int fr = 0; fr < 4; ++fr) {
          f32x4 rf = *(const f32x4*)(resc + fr * 16 + l4 * 4);
#pragma unroll
          for (int cf = 0; cf < 4; ++cf)
#pragma unroll
            for (int j = 0; j < 4; ++j) o[fr][cf][j] *= rf[j];
        }
      }
      bf16x8 pa[4];
#pragma unroll
      for (int fr = 0; fr < 4; ++fr)
        pa[fr] = *(const bf16x8*)((const char*)Ps + (fr * 16 + l15) * 80 + l4 * 16);
      __builtin_amdgcn_s_setprio(1);
#pragma unroll
      for (int fr = 0; fr < 4; ++fr)
#pragma unroll
        for (int cf = 0; cf < 4; ++cf)
          o[fr][cf] = __builtin_amdgcn_mfma_f32_16x16x32_bf16(
              pa[fr], *(const bf16x8*)&vreg[cf], o[fr][cf], 0, 0, 0);
      __builtin_amdgcn_s_setprio(0);
    }
    // no trailing barrier (hazards ordered by bar1/bar2 of adjacent iterations)
  }

  // ======== fused epilogue ========
  // R = relu(O/l) in regs; T = V-R -> Ts (bf16, swizzled, reuse Ks0..Ks1 span);
  // C = T @ W^T; Out = a*R + b*relu(C)
  const float av = ap[0], bv = bp[0];
#pragma unroll
  for (int fr = 0; fr < 4; ++fr) {
    f32x4 lv = *(const f32x4*)(lrow + fr * 16 + l4 * 4);
    f32x4 inv;
#pragma unroll
    for (int j = 0; j < 4; ++j) inv[j] = 1.f / lv[j];
#pragma unroll
    for (int cf = 0; cf < 4; ++cf)
#pragma unroll
      for (int j = 0; j < 4; ++j)
        o[fr][cf][j] = fmaxf(o[fr][cf][j] * inv[j], 0.f);  // o now holds R
  }
  // write T = V - R (swizzled bf16). All Ks reads done before bar1(63): safe.
  {
    u16* Ts = (u16*)smem;
#pragma unroll
    for (int fr = 0; fr < 4; ++fr)
#pragma unroll
      for (int cf = 0; cf < 4; ++cf) {
        const int col = wid * 64 + cf * 16 + l15;
#pragma unroll
        for (int j = 0; j < 4; ++j) {
          const int row = fr * 16 + l4 * 4 + j;
          float v = Vg[((size_t)(bat * 2048 + q0 + row)) * 512 + col];
          u16 t = f2bf(v - o[fr][cf][j]);
          *(u16*)((char*)Ts + row * 1024 + ((col * 2) ^ ((row & 7) << 4))) = t;
        }
      }
  }
  __syncthreads();  // T tile complete

  // projection GEMM: wave owns 64q x 64o (o-cols wid*64..+64), k=512
  f32x4 c2[4][4];
#pragma unroll
  for (int a = 0; a < 4; ++a)
#pragma unroll
    for (int b = 0; b < 4; ++b) c2[a][b] = (f32x4){0.f, 0.f, 0.f, 0.f};
  {
    const u16* Ts = (u16*)smem;
#pragma unroll
    for (int ks = 0; ks < 16; ++ks) {
      bf16x8 aT[4];
#pragma unroll
      for (int fr = 0; fr < 4; ++fr) {
        const int row = fr * 16 + l15;
        aT[fr] = *(const bf16x8*)((const char*)Ts + row * 1024 +
                                  ((ks * 64 + l4 * 16) ^ ((row & 7) << 4)));
      }
#pragma unroll
      for (int cf = 0; cf < 4; ++cf) {
        const int orow = wid * 64 + cf * 16 + l15;
        bf16x8 bw = *(const bf16x8*)(Wb + (size_t)orow * 512 + ks * 32 + l4 * 8);
#pragma unroll
        for (int fr = 0; fr < 4; ++fr)
          c2[fr][cf] = __builtin_amdgcn_mfma_f32_16x16x32_bf16(aT[fr], bw, c2[fr][cf], 0, 0, 0);
      }
    }
  }
  // combine + store
#pragma unroll
  for (int fr = 0; fr < 4; ++fr)
#pragma unroll
    for (int cf = 0; cf < 4; ++cf) {
      const int col = wid * 64 + cf * 16 + l15;
#pragma unroll
      for (int j = 0; j < 4; ++j) {
        const int row = fr * 16 + l4 * 4 + j;
        float c = fmaxf(c2[fr][cf][j], 0.f);
        Out[((size_t)(bat * 2048 + q0 + row)) * 512 + col] = av * o[fr][cf][j] + bv * c;
      }
    }
}

extern "C" void kernel_launch(void* const* d_in, const int* in_sizes, int n_in,
                              void* d_out, int out_size, void* d_ws, size_t ws_size,
                              hipStream_t stream) {
  const float* Q = (const float*)d_in[0];
  const float* K = (const float*)d_in[1];
  const float* V = (const float*)d_in[2];
  const float* W = (const float*)d_in[3];
  const float* sp = (const float*)d_in[4];
  const float* ap = (const float*)d_in[5];
  const float* bp = (const float*)d_in[6];
  float* out = (float*)d_out;

  const long long tEl = 8LL * 2048 * 512;  // 8388608 elems per tensor
  u16* Kb = (u16*)d_ws;
  u16* Vt = Kb + tEl;
  u16* Wb = Vt + tEl;

  cvt_bf16_kernel<<<4096, 256, 0, stream>>>(K, Kb, tEl / 8);
  cvt_bf16_kernel<<<128, 256, 0, stream>>>(W, Wb, (512LL * 512) / 8);
  transpose_v_kernel<<<dim3(32, 8, 8), 256, 0, stream>>>(V, Vt);

  hipFuncSetAttribute(reinterpret_cast<const void*>(attn_kernel),
                      hipFuncAttributeMaxDynamicSharedMemorySize, ATT_LDS);
  attn_kernel<<<dim3(8, 32), 512, ATT_LDS, stream>>>(Q, Kb, Vt, V, Wb, sp, ap, bp, out);
}